// Round 10
// baseline (2176.899 us; speedup 1.0000x reference)
//
#include <hip/hip_runtime.h>

// DictLearn: W column-normalize -> power method (100 it) -> IHT sparse coding
// (50 it, K=64 hard threshold) -> X = W @ Gamma.
// Outputs in d_out: X [512*1024] fp32, Gamma [1024*1024] fp32, norms [50] fp32.
//
// R15 changes vs R14:
//  * power chain: 51 serial k_pmv launches -> 7 k_pchain launches of 8
//    fused stages each. Stage s+1 blocks poll a per-stage counter until
//    stage s's 128 blocks release-increment it (R7's verified agent-scope
//    atomic pattern; narrower wait than R7's full-grid barrier). 1024
//    blocks @ launch_bounds(256,4) -> 4 blocks/CU guaranteed -> all
//    co-resident, no dispatch-order assumption, deadlock-free. Per-row dot
//    math identical to k_pmv (LDS-staged v, same float4 fmaf chain) ->
//    eta bit-identical -> IHT trajectory untouched.
//  * counters zeroed each invocation in k_colnorm (they end at 128).
//  * k_iht_all / k_front / k_back unchanged from R14.

#define DEV __device__ __forceinline__

constexpr int Nd = 512;    // signal dim
constexpr int Md = 1024;   // atoms
constexpr int Bd = 1024;   // batch
constexpr int Ksp = 64;    // sparsity K
constexpr int IHT = 50;

DEV float wave_reduce_f(float v) {
#pragma unroll
  for (int off = 32; off > 0; off >>= 1) v += __shfl_down(v, off);
  return v;
}
DEV double wave_reduce_d(double v) {
#pragma unroll
  for (int off = 32; off > 0; off >>= 1) v += __shfl_down(v, off);
  return v;
}
DEV float rfl_f(float v) {
  return __uint_as_float(__builtin_amdgcn_readfirstlane(__float_as_uint(v)));
}
DEV float vload_f(const float* p) {
  return __hip_atomic_load(p, __ATOMIC_RELAXED, __HIP_MEMORY_SCOPE_AGENT);
}
DEV void vstore_f(float* p, float v) {
  __hip_atomic_store(p, v, __ATOMIC_RELAXED, __HIP_MEMORY_SCOPE_AGENT);
}

__global__ __launch_bounds__(256) void k_colnorm(const float* __restrict__ W,
                                                 float* __restrict__ cnorm,
                                                 double* __restrict__ dacc,
                                                 unsigned* __restrict__ pcnt) {
  if (blockIdx.x == 0) {
    if (threadIdx.x < 51) dacc[threadIdx.x] = 0.0;           // was k_zero
    if (threadIdx.x >= 64 && threadIdx.x < 128) pcnt[threadIdx.x - 64] = 0u;
  }
  int col = blockIdx.x * 256 + threadIdx.x;  // 1024 cols
  double ss = 0.0;
  for (int i = 0; i < Nd; ++i) {
    float w = W[(size_t)i * Md + col];
    ss = fma((double)w, (double)w, ss);
  }
  cnorm[col] = (float)sqrt(ss);
}

__global__ __launch_bounds__(256) void k_normalize(const float* __restrict__ W,
                                                   const float* __restrict__ cnorm,
                                                   float* __restrict__ Wn) {
  int idx = blockIdx.x * 256 + threadIdx.x;  // 512*1024
  Wn[idx] = W[idx] / cnorm[idx & (Md - 1)];
}

// C[m,n] = scale * sum_k A(m,k)*B(k,n); ta/tb: operand stored transposed.
// BMxBN tile, 256 threads, 4xTN per thread, BK=32, register double-buffered
// staging. Per-element accumulation k0-ascending, kk-ascending (bit-stable).
// Shared passed by pointer so the body can live inside fused kernels;
// indexing arithmetic identical to the original k_gemm_t.
template <int BM, int BN, int TN>
DEV void gemm_dev(float* __restrict__ AsB, float* __restrict__ BsB,
                  const float* __restrict__ A, int lda, int ta,
                  const float* __restrict__ B, int ldb, int tb,
                  float* __restrict__ C, int ldc, int Kd, float scale,
                  int bx, int by) {
  constexpr int AE = 32 * BM / 256;
  constexpr int BE = 32 * BN / 256;
  constexpr int AS = BM + 4;   // row stride of As [32][BM+4]
  constexpr int BS = BN + 4;   // row stride of Bs [32][BN+4]
  const int tid = threadIdx.x;
  const int tx = tid % (BN / TN), ty = tid / (BN / TN);
  const int m0 = by * BM, n0 = bx * BN;
  float ra[AE], rb[BE];
  float acc[4][TN];
#pragma unroll
  for (int i = 0; i < 4; ++i)
#pragma unroll
    for (int j = 0; j < TN; ++j) acc[i][j] = 0.f;

  auto loadA = [&](int k0) {
    if (!ta) {
      const int c = tid & 31, r0 = tid >> 5;
#pragma unroll
      for (int i = 0; i < AE; ++i)
        ra[i] = A[(size_t)(m0 + r0 + i * 8) * lda + (k0 + c)];
    } else {
      const int r = tid % BM, c0 = tid / BM;
#pragma unroll
      for (int i = 0; i < AE; ++i)
        ra[i] = A[(size_t)(k0 + c0 + i * (256 / BM)) * lda + (m0 + r)];
    }
  };
  auto storeA = [&]() {
    if (!ta) {
      const int c = tid & 31, r0 = tid >> 5;
#pragma unroll
      for (int i = 0; i < AE; ++i) AsB[c * AS + r0 + i * 8] = ra[i];
    } else {
      const int r = tid % BM, c0 = tid / BM;
#pragma unroll
      for (int i = 0; i < AE; ++i) AsB[(c0 + i * (256 / BM)) * AS + r] = ra[i];
    }
  };
  auto loadB = [&](int k0) {
    if (!tb) {
      const int c = tid % BN, r0 = tid / BN;
#pragma unroll
      for (int i = 0; i < BE; ++i)
        rb[i] = B[(size_t)(k0 + r0 + i * (256 / BN)) * ldb + (n0 + c)];
    } else {
      const int r = tid & 31, c0 = tid >> 5;
#pragma unroll
      for (int i = 0; i < BE; ++i)
        rb[i] = B[(size_t)(n0 + c0 + i * 8) * ldb + (k0 + r)];
    }
  };
  auto storeB = [&]() {
    if (!tb) {
      const int c = tid % BN, r0 = tid / BN;
#pragma unroll
      for (int i = 0; i < BE; ++i) BsB[(r0 + i * (256 / BN)) * BS + c] = rb[i];
    } else {
      const int r = tid & 31, c0 = tid >> 5;
#pragma unroll
      for (int i = 0; i < BE; ++i) BsB[r * BS + c0 + i * 8] = rb[i];
    }
  };

  loadA(0);
  loadB(0);
  storeA();
  storeB();
  __syncthreads();
  for (int k0 = 0; k0 < Kd; k0 += 32) {
    const bool more = (k0 + 32) < Kd;
    if (more) { loadA(k0 + 32); loadB(k0 + 32); }  // prefetch into regs
#pragma unroll
    for (int kk = 0; kk < 32; ++kk) {
      const float4 a4 = *(const float4*)&AsB[kk * AS + ty * 4];
      const float aa[4] = {a4.x, a4.y, a4.z, a4.w};
      float bb[TN];
      if constexpr (TN == 4) {
        const float4 b4 = *(const float4*)&BsB[kk * BS + tx * 4];
        bb[0] = b4.x; bb[1] = b4.y; bb[2] = b4.z; bb[3] = b4.w;
      } else {
        const float2 b2 = *(const float2*)&BsB[kk * BS + tx * 2];
        bb[0] = b2.x; bb[1] = b2.y;
      }
#pragma unroll
      for (int i = 0; i < 4; ++i)
#pragma unroll
        for (int j = 0; j < TN; ++j) acc[i][j] = fmaf(aa[i], bb[j], acc[i][j]);
    }
    if (more) {
      __syncthreads();
      storeA();
      storeB();
      __syncthreads();
    }
  }
#pragma unroll
  for (int i = 0; i < 4; ++i) {
    if constexpr (TN == 4) {
      float4 o;
      o.x = acc[i][0] * scale; o.y = acc[i][1] * scale;
      o.z = acc[i][2] * scale; o.w = acc[i][3] * scale;
      *(float4*)&C[(size_t)(m0 + ty * 4 + i) * ldc + n0 + tx * 4] = o;
    } else {
      float2 o;
      o.x = acc[i][0] * scale; o.y = acc[i][1] * scale;
      *(float2*)&C[(size_t)(m0 + ty * 4 + i) * ldc + n0 + tx * 2] = o;
    }
  }
}

template <int BM, int BN, int TN>
__global__ __launch_bounds__(256) void k_gemm_t(const float* __restrict__ A, int lda, int ta,
                                                const float* __restrict__ B, int ldb, int tb,
                                                float* __restrict__ C, int ldc, int Kd,
                                                float scale) {
  __shared__ __align__(16) float smem[32 * (BM + 4) + 32 * (BN + 4)];
  gemm_dev<BM, BN, TN>(smem, smem + 32 * (BM + 4), A, lda, ta, B, ldb, tb, C,
                       ldc, Kd, scale, blockIdx.x, blockIdx.y);
}

// XLA ErfInvF32 (Giles) — matches jax/XLA erf_inv on f32.
DEV float erfinv_xla(float x) {
  float w = -log1pf(-x * x);
  float p;
  if (w < 5.0f) {
    w = w - 2.5f;
    p = 2.81022636e-08f;
    p = fmaf(p, w, 3.43273939e-07f);
    p = fmaf(p, w, -3.5233877e-06f);
    p = fmaf(p, w, -4.39150654e-06f);
    p = fmaf(p, w, 0.00021858087f);
    p = fmaf(p, w, -0.00125372503f);
    p = fmaf(p, w, -0.00417768164f);
    p = fmaf(p, w, 0.246640727f);
    p = fmaf(p, w, 1.50140941f);
  } else {
    w = sqrtf(w) - 3.0f;
    p = -0.000200214257f;
    p = fmaf(p, w, 0.000100950558f);
    p = fmaf(p, w, 0.00134934322f);
    p = fmaf(p, w, -0.00367342844f);
    p = fmaf(p, w, 0.00573950773f);
    p = fmaf(p, w, -0.0076224613f);
    p = fmaf(p, w, 0.00943887047f);
    p = fmaf(p, w, 1.00167406f);
    p = fmaf(p, w, 2.83297682f);
  }
  return p * x;
}

#define TF_ROUND(r)                                  \
  {                                                  \
    x0 += x1;                                        \
    x1 = (x1 << (r)) | (x1 >> (32 - (r)));           \
    x1 ^= x0;                                        \
  }

DEV float x0_value(unsigned i, int hi) {
  // threefry2x32(key=42) counter pair (i, i+512), bit-exact k_x0 math
  unsigned x0 = i, x1 = i + 512u;
  const unsigned ks0 = 0u, ks1 = 42u, ks2 = 0x1BD11BDAu ^ 42u;
  x0 += ks0; x1 += ks1;
  TF_ROUND(13) TF_ROUND(15) TF_ROUND(26) TF_ROUND(6)  x0 += ks1; x1 += ks2 + 1u;
  TF_ROUND(17) TF_ROUND(29) TF_ROUND(16) TF_ROUND(24) x0 += ks2; x1 += ks0 + 2u;
  TF_ROUND(13) TF_ROUND(15) TF_ROUND(26) TF_ROUND(6)  x0 += ks0; x1 += ks1 + 3u;
  TF_ROUND(17) TF_ROUND(29) TF_ROUND(16) TF_ROUND(24) x0 += ks1; x1 += ks2 + 4u;
  TF_ROUND(13) TF_ROUND(15) TF_ROUND(26) TF_ROUND(6)  x0 += ks2; x1 += ks0 + 5u;
  const float lo = -0.99999994f;      // nextafter(-1, 0) in f32
  const float sqrt2 = 1.41421356237f; // rounds to 0x3FB504F3
  const unsigned bits = hi ? x1 : x0;
  float f = __uint_as_float((bits >> 9) | 0x3f800000u) - 1.0f;
  float u = fmaxf(lo, f * 2.0f + lo);  // (hi-lo) == 2.0f exactly in f32
  return sqrt2 * erfinv_xla(u);
}

// Fused prologue: blocks 0..127 Smat GEMM, 128..383 Q GEMM, 384..639 YW GEMM,
// 640..767 yn2, 768..895 z0. All independent (need only Wn, Y); per-block
// code identical to the former standalone launches -> bit-exact.
__global__ __launch_bounds__(256) void k_front(
    const float* __restrict__ Wn, const float* __restrict__ Y,
    float* __restrict__ Smat, float* __restrict__ Qm, float* __restrict__ YWm,
    double* __restrict__ dacc, float* __restrict__ vout) {
  __shared__ __align__(16) float smem[4352];  // 17408 B, carved per role
  const int i = blockIdx.x;
  const int t = threadIdx.x;
  if (i < 128) {
    gemm_dev<64, 32, 2>(smem, smem + 32 * 68, Wn, Md, 0, Wn, Md, 1, Smat, Nd,
                        Md, 1.0f, i % 16, i / 16);
  } else if (i < 384) {
    const int j = i - 128;
    gemm_dev<64, 64, 4>(smem, smem + 32 * 68, Wn, Md, 1, Wn, Md, 0, Qm, Md,
                        Nd, 1.0f, j % 16, j / 16);
  } else if (i < 640) {
    const int j = i - 384;
    gemm_dev<64, 64, 4>(smem, smem + 32 * 68, Y, Nd, 0, Wn, Md, 0, YWm, Md,
                        Nd, 1.0f, j % 16, j / 16);
  } else if (i < 768) {
    // yn2 body (was <<<128,256>>>): block index j, stride 128*256
    const int j = i - 640;
    double* red = (double*)smem;
    double s = 0.0;
    for (int idx = j * 256 + t; idx < Bd * Nd; idx += 128 * 256) {
      float y = Y[idx];
      s = fma((double)y, (double)y, s);
    }
    s = wave_reduce_d(s);
    const int lane = t & 63, wid = t >> 6;
    if (lane == 0) red[wid] = s;
    __syncthreads();
    if (t == 0) atomicAdd(&dacc[0], red[0] + red[1] + red[2] + red[3]);
  } else {
    // z0 body (was <<<128,256>>>): X0 recomputed in LDS (bit-exact)
    const int j = i - 768;
    float* x0s = smem;
    x0s[t] = x0_value((unsigned)t, 0);
    x0s[t + 512] = x0_value((unsigned)t, 1);
    x0s[t + 256] = x0_value((unsigned)(t + 256), 0);
    x0s[t + 768] = x0_value((unsigned)(t + 256), 1);
    __syncthreads();
    const int lane = t & 63, wid = t >> 6;
    const int row = j * 4 + wid;  // < 512
    const float4* wr = (const float4*)(Wn + (size_t)row * Md);
    const float4* x4 = (const float4*)x0s;
    float s = 0.f;
#pragma unroll
    for (int e = 0; e < 4; ++e) {
      const float4 w4 = wr[lane + e * 64];
      const float4 xx = x4[lane + e * 64];
      s = fmaf(w4.x, xx.x, s); s = fmaf(w4.y, xx.y, s);
      s = fmaf(w4.z, xx.z, s); s = fmaf(w4.w, xx.w, s);
    }
    s = wave_reduce_f(s);
    if (lane == 0) vout[row] = s;
  }
}

// Fused power chain: 8 stages per launch, 128 blocks per stage.
// Stage g: v[g+1] = (v[g] @ M) * scale, M/scale per g (g<49: S2,1.0;
// g=49,50: Smat,0.125). Per-row dot math identical to the old k_pmv
// (LDS-staged input, same float4 fmaf chain, same shuffle reduce) ->
// bit-identical vectors -> eta bit-identical.
// Slots in vbase: vstage[g] -> g&1 for g<=49, slot2 for g=50, slot3 = final.
// Co-residency: <=1024 blocks @ launch_bounds(256,4) -> >=4 blocks/CU ->
// all blocks resident; stage s polls cnt[s-1]==128 (release/acquire, AGENT).
__global__ __launch_bounds__(256, 4) void k_pchain(
    const float* __restrict__ S2m, const float* __restrict__ Smat,
    float* __restrict__ vbase, unsigned* __restrict__ cnt, int gbase) {
  __shared__ __align__(16) float vin_s[Nd];
  const int t = threadIdx.x, lane = t & 63, wid = t >> 6;
  const int st = blockIdx.x >> 7;    // stage within this launch
  const int idx = blockIdx.x & 127;  // block within stage
  const int g = gbase + st;          // global stage 0..50
  if (st > 0) {
    if (t == 0) {
      while (__hip_atomic_load(&cnt[g - 1], __ATOMIC_ACQUIRE,
                               __HIP_MEMORY_SCOPE_AGENT) < 128u)
        __builtin_amdgcn_s_sleep(8);
    }
    __syncthreads();
  }
  const float* src = vbase + ((g <= 49) ? ((g & 1) * Nd) : (2 * Nd));
  float* dst = vbase + ((g <= 48) ? (((g + 1) & 1) * Nd)
                                  : ((g == 49) ? 2 * Nd : 3 * Nd));
  const float* M = (g < 49) ? S2m : Smat;
  const float scale = (g < 49) ? 1.0f : 0.125f;
  vin_s[t] = vload_f(&src[t]);
  vin_s[t + 256] = vload_f(&src[t + 256]);
  __syncthreads();
  const int row = idx * 4 + wid;  // < 512
  const float4* mr = (const float4*)(M + (size_t)row * Nd);
  const float4* v4 = (const float4*)vin_s;
  float s = 0.f;
#pragma unroll
  for (int e = 0; e < 2; ++e) {
    const float4 m4 = mr[lane + e * 64];
    const float4 xx = v4[lane + e * 64];
    s = fmaf(m4.x, xx.x, s); s = fmaf(m4.y, xx.y, s);
    s = fmaf(m4.z, xx.z, s); s = fmaf(m4.w, xx.w, s);
  }
  s = wave_reduce_f(s);
  if (lane == 0) vstore_f(&dst[row], s * scale);
  __syncthreads();  // all stores issued before the release increment
  if (t == 0)
    __hip_atomic_fetch_add(&cnt[g], 1u, __ATOMIC_RELEASE,
                           __HIP_MEMORY_SCOPE_AGENT);
}

__global__ __launch_bounds__(512) void k_pfinal(const float* __restrict__ v99,
                                                const float* __restrict__ v100,
                                                float* __restrict__ cbuf) {
  __shared__ double r99[8], r100[8];
  const int t = threadIdx.x, lane = t & 63, wid = t >> 6;
  double a = (double)v99[t]; a *= a;
  double b = (double)v100[t]; b *= b;
  a = wave_reduce_d(a);
  b = wave_reduce_d(b);
  if (lane == 0) { r99[wid] = a; r100[wid] = b; }
  __syncthreads();
  if (t == 0) {
    double n99 = 0.0, n100 = 0.0;
    for (int i = 0; i < 8; ++i) { n99 += r99[i]; n100 += r100[i]; }
    float c = (float)(8.0 * sqrt(n100 / n99));  // last pre-norm ||X2||
    cbuf[0] = c;
    cbuf[1] = 1.0f / c;  // eta
  }
}

// ALL IHT iterations fused: one workgroup per batch row, loops it=-1..49.
// R12 version VERBATIM (620us): register Gamma, pipelined gather, peeled
// pass-3 barriers fused with norm-dot (10 barriers/iter).
__global__ __launch_bounds__(256, 4) void k_iht_all(
    const float* __restrict__ Q, const float* __restrict__ YW,
    const float* __restrict__ cbuf, float* __restrict__ gdense,
    double* __restrict__ normacc) {
  __shared__ float u[Md];   // holds P (gather result) for the norm dot
  __shared__ float yws[Md];
  __shared__ float sval[Ksp];
  __shared__ int sidx[Ksp];
  __shared__ unsigned histbuf[2][4][256];  // [parity][wave][bin]
  __shared__ unsigned wred[4];
  __shared__ unsigned sel_need, sel_prefix;
  __shared__ double dred0;
  __shared__ int scnt;

  const int t = threadIdx.x;
  const int b = blockIdx.x;
  const int lane = t & 63, wv = t >> 6;
  const float eta = cbuf[1];
  const float4 yw = ((const float4*)(YW + (size_t)b * Md))[t];  // row in regs
  ((float4*)yws)[t] = yw;                                        // + LDS copy
#pragma unroll
  for (int e = 0; e < 8; ++e) ((unsigned*)histbuf)[t + e * 256] = 0u;
  const float* Qt = Q + t * 4;  // per-thread column base; row base is scalar
  float gdr[4] = {0.f, 0.f, 0.f, 0.f};  // dense Gamma, own 4 cols, registers

  // wave-0 merged scan over 4 per-wave histograms; writes sel_prefix/sel_need.
  auto scan_select = [&](unsigned(*hist)[256], unsigned pfx, unsigned nd, int sh) {
    const unsigned c0 = hist[0][lane] + hist[1][lane] + hist[2][lane] + hist[3][lane];
    const unsigned c1 = hist[0][lane + 64] + hist[1][lane + 64] + hist[2][lane + 64] + hist[3][lane + 64];
    const unsigned c2 = hist[0][lane + 128] + hist[1][lane + 128] + hist[2][lane + 128] + hist[3][lane + 128];
    const unsigned c3 = hist[0][lane + 192] + hist[1][lane + 192] + hist[2][lane + 192] + hist[3][lane + 192];
    unsigned s0 = c0, s1 = c1, s2 = c2, s3 = c3;  // suffix scans (4 chunks)
#pragma unroll
    for (int off = 1; off < 64; off <<= 1) {
      const unsigned y0 = __shfl_down(s0, off), y1 = __shfl_down(s1, off);
      const unsigned y2 = __shfl_down(s2, off), y3 = __shfl_down(s3, off);
      if (lane + off < 64) { s0 += y0; s1 += y1; s2 += y2; s3 += y3; }
    }
    const unsigned T1 = __builtin_amdgcn_readfirstlane(s1);
    const unsigned T2 = __builtin_amdgcn_readfirstlane(s2);
    const unsigned T3 = __builtin_amdgcn_readfirstlane(s3);
    const unsigned i0 = s0 + T1 + T2 + T3;  // incl count, bin = lane
    const unsigned i1 = s1 + T2 + T3;       // bin = lane+64
    const unsigned i2 = s2 + T3;            // bin = lane+128
    const unsigned i3 = s3;                 // bin = lane+192
    if (i0 >= nd && i0 - c0 < nd) { sel_prefix = pfx | ((unsigned)lane << sh); sel_need = nd - (i0 - c0); }
    if (i1 >= nd && i1 - c1 < nd) { sel_prefix = pfx | ((unsigned)(lane + 64) << sh); sel_need = nd - (i1 - c1); }
    if (i2 >= nd && i2 - c2 < nd) { sel_prefix = pfx | ((unsigned)(lane + 128) << sh); sel_need = nd - (i2 - c2); }
    if (i3 >= nd && i3 - c3 < nd) { sel_prefix = pfx | ((unsigned)(lane + 192) << sh); sel_need = nd - (i3 - c3); }
  };

  for (int it = -1; it < IHT; ++it) {
    float vals[4];
    unsigned key[4];
    int cnt = 0;
    if (it >= 0) {
      cnt = scnt;
      float4 p = make_float4(0.f, 0.f, 0.f, 0.f);
      // double-buffered 8-row pipeline: issue next batch's loads before the
      // current batch's fmafs. Per-component k-ascending order -> bit-exact.
      float4 qa[8], qb[8];
      float ga[8], gb[8];
      auto LOAD8 = [&](float4* q, float* g, int kk) {
#pragma unroll
        for (int j = 0; j < 8; ++j) {
          const int id = __builtin_amdgcn_readfirstlane(sidx[kk + j]);
          g[j] = rfl_f(sval[kk + j]);
          q[j] = *(const float4*)(Qt + (size_t)id * Md);
        }
      };
      auto FMA8 = [&](const float4* q, const float* g) {
#pragma unroll
        for (int j = 0; j < 8; ++j) p.x = fmaf(g[j], q[j].x, p.x);
#pragma unroll
        for (int j = 0; j < 8; ++j) p.y = fmaf(g[j], q[j].y, p.y);
#pragma unroll
        for (int j = 0; j < 8; ++j) p.z = fmaf(g[j], q[j].z, p.z);
#pragma unroll
        for (int j = 0; j < 8; ++j) p.w = fmaf(g[j], q[j].w, p.w);
      };
      int k = 0;
      const int nfull = cnt & ~7;
      if (nfull >= 8) {
        LOAD8(qa, ga, 0);
        k = 8;
        for (; k + 16 <= nfull; k += 16) {
          LOAD8(qb, gb, k);
          FMA8(qa, ga);
          LOAD8(qa, ga, k + 8);
          FMA8(qb, gb);
        }
        if (k + 8 <= nfull) {  // one full batch beyond qa remains
          LOAD8(qb, gb, k);
          FMA8(qa, ga);
          FMA8(qb, gb);
          k += 8;
        } else {
          FMA8(qa, ga);
        }
      }
      for (; k < cnt; ++k) {
        const int id = __builtin_amdgcn_readfirstlane(sidx[k]);
        const float g = rfl_f(sval[k]);
        const float4 q = *(const float4*)(Qt + (size_t)id * Md);
        p.x = fmaf(g, q.x, p.x); p.y = fmaf(g, q.y, p.y);
        p.z = fmaf(g, q.z, p.z); p.w = fmaf(g, q.w, p.w);
      }
      ((float4*)u)[t] = p;  // u holds P for the norm dot (read by wave 1)
      // U = uu + Gamma_dense, entirely in registers
      vals[0] = -(eta * (p.x - yw.x)) + gdr[0];
      vals[1] = -(eta * (p.y - yw.y)) + gdr[1];
      vals[2] = -(eta * (p.z - yw.z)) + gdr[2];
      vals[3] = -(eta * (p.w - yw.w)) + gdr[3];
      // no barrier here: histbuf[1] was zeroed last iteration (pass-0 phase,
      // >=2 barriers ago); F1 below covers P visibility + pass-3 atomics.
    } else {
      vals[0] = eta * yw.x; vals[1] = eta * yw.y;
      vals[2] = eta * yw.z; vals[3] = eta * yw.w;
      __syncthreads();      // B0: init zeros of histbuf + yws visible
    }
#pragma unroll
    for (int e = 0; e < 4; ++e) key[e] = __float_as_uint(vals[e]) & 0x7fffffffu;

    // ---- peeled radix pass 3 (pb=1): atomics by all waves ----
#pragma unroll
    for (int e = 0; e < 4; ++e) atomicAdd(&histbuf[1][wv][key[e] >> 24], 1u);
    __syncthreads();  // F1: P (u[]) + pass-3 atomics visible
    // ---- specialized phase: scan | norm-dot | re-zero histbuf[0] ----
    if (wv == 0) {
      scan_select(histbuf[1], 0u, Ksp + 1, 24);
    } else if (wv == 1) {
      if (it >= 1) {
        // norm-dot: cnt <= 64, one wave. Same per-lane mapping and shuffle
        // reduce tree as R8's wave-0 computation -> bit-identical sum.
        double part = 0.0;
        if (lane < cnt) {
          const int id = sidx[lane];
          part = (double)sval[lane] * ((double)u[id] - 2.0 * (double)yws[id]);
        }
        part = wave_reduce_d(part);
        if (lane == 0) dred0 = part;
      }
    } else {
      // waves 2,3: zero histbuf[0] (1024 words; last read: previous
      // iteration's pass-0 scan, >=3 barriers ago). 512 words per wave.
      unsigned* hz = (unsigned*)histbuf[0] + (wv - 2) * 512;
#pragma unroll
      for (int e = 0; e < 8; ++e) hz[lane + e * 64] = 0u;
    }
    __syncthreads();  // F2: sel_*, dred0, zeros visible
    unsigned prefix = sel_prefix;
    unsigned need = sel_need;
    unsigned pmask = 0xFF000000u;

    // ---- radix passes 2..0 (parallel, 2 barriers each) ----
#pragma unroll
    for (int pass = 2; pass >= 0; --pass) {
      const int sh = 8 * pass;
      const int pb = pass & 1;  // 0,1,0
      unsigned(*hist)[256] = histbuf[pb];
#pragma unroll
      for (int e = 0; e < 4; ++e)
        if ((key[e] & pmask) == prefix) atomicAdd(&hist[wv][(key[e] >> sh) & 255u], 1u);
      if (pass == 2 && it >= 1 && t == 0) atomicAdd(&normacc[it - 1], dred0);
      __syncthreads();  // A: atomics visible
      // zero the opposite buffer (next pass / next iteration's pass 3)
      unsigned* hz = histbuf[pb ^ 1][wv];
      hz[lane] = 0u; hz[lane + 64] = 0u; hz[lane + 128] = 0u; hz[lane + 192] = 0u;
      if (wv == 0) scan_select(hist, prefix, need, sh);
      __syncthreads();  // B: sel_* and zeros visible
      prefix = sel_prefix;
      need = sel_need;
      pmask |= (255u << sh);
    }
    const unsigned Tbits = prefix;

    // ---- ordered compaction (deterministic, ascending column order) ----
    unsigned keep = 0u;
    unsigned myc = 0u;
#pragma unroll
    for (int e = 0; e < 4; ++e)
      if (key[e] > Tbits) { keep |= (1u << e); ++myc; }
    // update dense-Gamma registers for next iteration
    gdr[0] = (keep & 1u) ? vals[0] : 0.f;
    gdr[1] = (keep & 2u) ? vals[1] : 0.f;
    gdr[2] = (keep & 4u) ? vals[2] : 0.f;
    gdr[3] = (keep & 8u) ? vals[3] : 0.f;
    unsigned x = myc;
#pragma unroll
    for (int off = 1; off < 64; off <<= 1) {  // wave inclusive prefix scan
      const unsigned y = __shfl_up(x, off);
      if (lane >= off) x += y;
    }
    if (lane == 63) wred[wv] = x;  // wave total
    __syncthreads();  // C1: wred visible (old sidx/sval reads done pre-F2)
    unsigned addlo = 0u;
    for (int w2 = 0; w2 < wv; ++w2) addlo += wred[w2];
    int base = (int)(x + addlo) - (int)myc;  // exclusive prefix in thread order
#pragma unroll
    for (int e = 0; e < 4; ++e) {
      if (keep & (1u << e)) {
        sidx[base] = t * 4 + e;
        sval[base] = vals[e];
        ++base;
      }
    }
    if (t == 0) scnt = (int)(wred[0] + wred[1] + wred[2] + wred[3]);
    if (it == IHT - 1) {
      float4 g;
      g.x = gdr[0]; g.y = gdr[1]; g.z = gdr[2]; g.w = gdr[3];
      ((float4*)(gdense + (size_t)b * Md))[t] = g;
    }
    __syncthreads();  // C2: publish sidx/sval/scnt for next iteration
  }

  // ---- epilogue: norms[49] term for final Gamma (same math as R3 k_norm50) --
  const int cnt = scnt;
  if (wv == 0) {
    double part = 0.0;
    if (lane < cnt) {
      const int id = sidx[lane];
      float acc2 = 0.f;
      for (int k = 0; k < cnt; ++k)
        acc2 = fmaf(sval[k], Q[(size_t)sidx[k] * Md + id], acc2);
      part = (double)sval[lane] * ((double)acc2 - 2.0 * (double)yws[id]);
    }
    part = wave_reduce_d(part);
    if (lane == 0) atomicAdd(&normacc[IHT - 1], part);
  }
}

// Fused epilogue: blocks 0..255 X = Wn @ Gamma GEMM; block 256 computes norms.
__global__ __launch_bounds__(256) void k_back(
    const float* __restrict__ Wn, const float* __restrict__ G,
    float* __restrict__ X, const double* __restrict__ dacc,
    float* __restrict__ onorms) {
  __shared__ __align__(16) float smem[4352];
  const int i = blockIdx.x;
  if (i < 256) {
    gemm_dev<64, 32, 2>(smem, smem + 32 * 68, Wn, Md, 0, G, Md, 0, X, Md, Md,
                        1.0f, i % 32, i / 32);
  } else {
    const int t = threadIdx.x;
    if (t < IHT) {
      const double yn2 = dacc[0];
      double r2 = yn2 + dacc[1 + t];
      if (r2 < 0.0) r2 = 0.0;
      onorms[t] = (float)(sqrt(r2) / sqrt(yn2));
    }
  }
}

extern "C" void kernel_launch(void* const* d_in, const int* in_sizes, int n_in,
                              void* d_out, int out_size, void* d_ws, size_t ws_size,
                              hipStream_t stream) {
  (void)in_sizes; (void)n_in; (void)out_size; (void)ws_size;  // K hardcoded = 64
  const float* Y = (const float*)d_in[0];  // [1024,512]
  const float* W = (const float*)d_in[1];  // [512,1024]
  float* out = (float*)d_out;
  float* outX = out;                   // [512,1024]
  float* outG = out + Nd * Md;         // [1024,1024]
  float* outN = outG + Bd * Md;        // [50]

  // workspace layout (~11.5 MB)
  char* wsb = (char*)d_ws;
  double* dacc = (double*)wsb;               // 51 doubles
  float* cbuf = (float*)(wsb + 512);         // [0]=c, [1]=eta
  float* Wn = (float*)(wsb + 1024);          // 512*1024
  float* Q = Wn + Nd * Md;                   // 1024*1024
  float* YW = Q + Md * Md;                   // 1024*1024
  float* Smat = YW + Bd * Md;                // 512*512
  float* S2 = Smat + Nd * Nd;                // 512*512
  float* cnorm = S2 + Nd * Nd;               // 1024
  float* X0 = cnorm + Md;                    // 1024 (unused, kept for layout)
  float* V = X0 + Md;                        // 4*512 power-iter slots
  unsigned* pcnt = (unsigned*)(V + 2048);    // 51 stage counters (R7's spot)

  k_colnorm<<<4, 256, 0, stream>>>(W, cnorm, dacc, pcnt);  // zeroes dacc+pcnt
  k_normalize<<<2048, 256, 0, stream>>>(W, cnorm, Wn);

  // fused independent prologue: Smat = Wn Wn^T, Q = Wn^T Wn, YW = Y Wn,
  // Yn2 accumulation, z0 = X0 @ Wn^T — one 896-block launch.
  k_front<<<896, 256, 0, stream>>>(Wn, Y, Smat, Q, YW, dacc, V);

  // S2 = Smat*Smat/64 (depends on Smat)
  k_gemm_t<64, 32, 2><<<dim3(16, 8), 256, 0, stream>>>(Smat, Nd, 0, Smat, Nd, 0, S2, Nd, Nd, 0.015625f);

  // power chain: 51 MV stages (49x S2 + 2x Smat/8), 8 stages per launch.
  // Math bit-identical to the former 51 k_pmv launches.
  for (int l = 0; l < 51; l += 8) {
    const int ns = (51 - l < 8) ? (51 - l) : 8;
    k_pchain<<<ns * 128, 256, 0, stream>>>(S2, Smat, V, pcnt, l);
  }
  k_pfinal<<<1, 512, 0, stream>>>(V + 1024, V + 1536, cbuf);

  // IHT: init + 50 iterations + final norm term, all in ONE launch
  k_iht_all<<<1024, 256, 0, stream>>>(Q, YW, cbuf, outG, dacc + 1);

  // fused epilogue: X = Wn @ Gamma + norms finalize
  k_back<<<257, 256, 0, stream>>>(Wn, outG, outX, dacc, outN);
}

// Round 11
// 875.255 us; speedup vs baseline: 2.4872x; 2.4872x over previous
//
#include <hip/hip_runtime.h>

// DictLearn: W column-normalize -> power method (100 it) -> IHT sparse coding
// (50 it, K=64 hard threshold) -> X = W @ Gamma.
// Outputs in d_out: X [512*1024] fp32, Gamma [1024*1024] fp32, norms [50] fp32.
//
// R16 = R14 verbatim (best verified: 881.0 us).
// R15's 8-stage counter-fused power chain REVERTED: ~896 blocks spinning on
// one counter line across 8 non-coherent XCD L2s collapsed to 2177 us total.
// Thrice-confirmed lesson (R7 persistent grid-bar +30us, R15 counter chain
// +1300us): on MI355X, inter-block sync via global atomics >= launch cost
// unless poller count is tiny; the serial launch chain IS the cheap form.
//
// Structure:
//  * k_iht_all (R12 form, 620us): register Gamma, double-buffered 8-row
//    gather pipeline, 10 barriers/iter with pass-3 scan/norm-dot/zeroing
//    fused into one wave-specialized phase.
//  * k_front: one 896-block launch for {Smat, Q, YW GEMMs, yn2, z0}.
//  * k_back: X-GEMM + norms finalize.
//  * power method: serial k_pmv chain (bit-identical eta).

#define DEV __device__ __forceinline__

constexpr int Nd = 512;    // signal dim
constexpr int Md = 1024;   // atoms
constexpr int Bd = 1024;   // batch
constexpr int Ksp = 64;    // sparsity K
constexpr int IHT = 50;

DEV float wave_reduce_f(float v) {
#pragma unroll
  for (int off = 32; off > 0; off >>= 1) v += __shfl_down(v, off);
  return v;
}
DEV double wave_reduce_d(double v) {
#pragma unroll
  for (int off = 32; off > 0; off >>= 1) v += __shfl_down(v, off);
  return v;
}
DEV float rfl_f(float v) {
  return __uint_as_float(__builtin_amdgcn_readfirstlane(__float_as_uint(v)));
}

__global__ __launch_bounds__(256) void k_colnorm(const float* __restrict__ W,
                                                 float* __restrict__ cnorm,
                                                 double* __restrict__ dacc) {
  if (blockIdx.x == 0 && threadIdx.x < 51) dacc[threadIdx.x] = 0.0;  // was k_zero
  int col = blockIdx.x * 256 + threadIdx.x;  // 1024 cols
  double ss = 0.0;
  for (int i = 0; i < Nd; ++i) {
    float w = W[(size_t)i * Md + col];
    ss = fma((double)w, (double)w, ss);
  }
  cnorm[col] = (float)sqrt(ss);
}

__global__ __launch_bounds__(256) void k_normalize(const float* __restrict__ W,
                                                   const float* __restrict__ cnorm,
                                                   float* __restrict__ Wn) {
  int idx = blockIdx.x * 256 + threadIdx.x;  // 512*1024
  Wn[idx] = W[idx] / cnorm[idx & (Md - 1)];
}

// C[m,n] = scale * sum_k A(m,k)*B(k,n); ta/tb: operand stored transposed.
// BMxBN tile, 256 threads, 4xTN per thread, BK=32, register double-buffered
// staging. Per-element accumulation k0-ascending, kk-ascending (bit-stable).
// Shared passed by pointer so the body can live inside fused kernels;
// indexing arithmetic identical to the original k_gemm_t.
template <int BM, int BN, int TN>
DEV void gemm_dev(float* __restrict__ AsB, float* __restrict__ BsB,
                  const float* __restrict__ A, int lda, int ta,
                  const float* __restrict__ B, int ldb, int tb,
                  float* __restrict__ C, int ldc, int Kd, float scale,
                  int bx, int by) {
  constexpr int AE = 32 * BM / 256;
  constexpr int BE = 32 * BN / 256;
  constexpr int AS = BM + 4;   // row stride of As [32][BM+4]
  constexpr int BS = BN + 4;   // row stride of Bs [32][BN+4]
  const int tid = threadIdx.x;
  const int tx = tid % (BN / TN), ty = tid / (BN / TN);
  const int m0 = by * BM, n0 = bx * BN;
  float ra[AE], rb[BE];
  float acc[4][TN];
#pragma unroll
  for (int i = 0; i < 4; ++i)
#pragma unroll
    for (int j = 0; j < TN; ++j) acc[i][j] = 0.f;

  auto loadA = [&](int k0) {
    if (!ta) {
      const int c = tid & 31, r0 = tid >> 5;
#pragma unroll
      for (int i = 0; i < AE; ++i)
        ra[i] = A[(size_t)(m0 + r0 + i * 8) * lda + (k0 + c)];
    } else {
      const int r = tid % BM, c0 = tid / BM;
#pragma unroll
      for (int i = 0; i < AE; ++i)
        ra[i] = A[(size_t)(k0 + c0 + i * (256 / BM)) * lda + (m0 + r)];
    }
  };
  auto storeA = [&]() {
    if (!ta) {
      const int c = tid & 31, r0 = tid >> 5;
#pragma unroll
      for (int i = 0; i < AE; ++i) AsB[c * AS + r0 + i * 8] = ra[i];
    } else {
      const int r = tid % BM, c0 = tid / BM;
#pragma unroll
      for (int i = 0; i < AE; ++i) AsB[(c0 + i * (256 / BM)) * AS + r] = ra[i];
    }
  };
  auto loadB = [&](int k0) {
    if (!tb) {
      const int c = tid % BN, r0 = tid / BN;
#pragma unroll
      for (int i = 0; i < BE; ++i)
        rb[i] = B[(size_t)(k0 + r0 + i * (256 / BN)) * ldb + (n0 + c)];
    } else {
      const int r = tid & 31, c0 = tid >> 5;
#pragma unroll
      for (int i = 0; i < BE; ++i)
        rb[i] = B[(size_t)(n0 + c0 + i * 8) * ldb + (k0 + r)];
    }
  };
  auto storeB = [&]() {
    if (!tb) {
      const int c = tid % BN, r0 = tid / BN;
#pragma unroll
      for (int i = 0; i < BE; ++i) BsB[(r0 + i * (256 / BN)) * BS + c] = rb[i];
    } else {
      const int r = tid & 31, c0 = tid >> 5;
#pragma unroll
      for (int i = 0; i < BE; ++i) BsB[r * BS + c0 + i * 8] = rb[i];
    }
  };

  loadA(0);
  loadB(0);
  storeA();
  storeB();
  __syncthreads();
  for (int k0 = 0; k0 < Kd; k0 += 32) {
    const bool more = (k0 + 32) < Kd;
    if (more) { loadA(k0 + 32); loadB(k0 + 32); }  // prefetch into regs
#pragma unroll
    for (int kk = 0; kk < 32; ++kk) {
      const float4 a4 = *(const float4*)&AsB[kk * AS + ty * 4];
      const float aa[4] = {a4.x, a4.y, a4.z, a4.w};
      float bb[TN];
      if constexpr (TN == 4) {
        const float4 b4 = *(const float4*)&BsB[kk * BS + tx * 4];
        bb[0] = b4.x; bb[1] = b4.y; bb[2] = b4.z; bb[3] = b4.w;
      } else {
        const float2 b2 = *(const float2*)&BsB[kk * BS + tx * 2];
        bb[0] = b2.x; bb[1] = b2.y;
      }
#pragma unroll
      for (int i = 0; i < 4; ++i)
#pragma unroll
        for (int j = 0; j < TN; ++j) acc[i][j] = fmaf(aa[i], bb[j], acc[i][j]);
    }
    if (more) {
      __syncthreads();
      storeA();
      storeB();
      __syncthreads();
    }
  }
#pragma unroll
  for (int i = 0; i < 4; ++i) {
    if constexpr (TN == 4) {
      float4 o;
      o.x = acc[i][0] * scale; o.y = acc[i][1] * scale;
      o.z = acc[i][2] * scale; o.w = acc[i][3] * scale;
      *(float4*)&C[(size_t)(m0 + ty * 4 + i) * ldc + n0 + tx * 4] = o;
    } else {
      float2 o;
      o.x = acc[i][0] * scale; o.y = acc[i][1] * scale;
      *(float2*)&C[(size_t)(m0 + ty * 4 + i) * ldc + n0 + tx * 2] = o;
    }
  }
}

template <int BM, int BN, int TN>
__global__ __launch_bounds__(256) void k_gemm_t(const float* __restrict__ A, int lda, int ta,
                                                const float* __restrict__ B, int ldb, int tb,
                                                float* __restrict__ C, int ldc, int Kd,
                                                float scale) {
  __shared__ __align__(16) float smem[32 * (BM + 4) + 32 * (BN + 4)];
  gemm_dev<BM, BN, TN>(smem, smem + 32 * (BM + 4), A, lda, ta, B, ldb, tb, C,
                       ldc, Kd, scale, blockIdx.x, blockIdx.y);
}

// XLA ErfInvF32 (Giles) — matches jax/XLA erf_inv on f32.
DEV float erfinv_xla(float x) {
  float w = -log1pf(-x * x);
  float p;
  if (w < 5.0f) {
    w = w - 2.5f;
    p = 2.81022636e-08f;
    p = fmaf(p, w, 3.43273939e-07f);
    p = fmaf(p, w, -3.5233877e-06f);
    p = fmaf(p, w, -4.39150654e-06f);
    p = fmaf(p, w, 0.00021858087f);
    p = fmaf(p, w, -0.00125372503f);
    p = fmaf(p, w, -0.00417768164f);
    p = fmaf(p, w, 0.246640727f);
    p = fmaf(p, w, 1.50140941f);
  } else {
    w = sqrtf(w) - 3.0f;
    p = -0.000200214257f;
    p = fmaf(p, w, 0.000100950558f);
    p = fmaf(p, w, 0.00134934322f);
    p = fmaf(p, w, -0.00367342844f);
    p = fmaf(p, w, 0.00573950773f);
    p = fmaf(p, w, -0.0076224613f);
    p = fmaf(p, w, 0.00943887047f);
    p = fmaf(p, w, 1.00167406f);
    p = fmaf(p, w, 2.83297682f);
  }
  return p * x;
}

#define TF_ROUND(r)                                  \
  {                                                  \
    x0 += x1;                                        \
    x1 = (x1 << (r)) | (x1 >> (32 - (r)));           \
    x1 ^= x0;                                        \
  }

DEV float x0_value(unsigned i, int hi) {
  // threefry2x32(key=42) counter pair (i, i+512), bit-exact k_x0 math
  unsigned x0 = i, x1 = i + 512u;
  const unsigned ks0 = 0u, ks1 = 42u, ks2 = 0x1BD11BDAu ^ 42u;
  x0 += ks0; x1 += ks1;
  TF_ROUND(13) TF_ROUND(15) TF_ROUND(26) TF_ROUND(6)  x0 += ks1; x1 += ks2 + 1u;
  TF_ROUND(17) TF_ROUND(29) TF_ROUND(16) TF_ROUND(24) x0 += ks2; x1 += ks0 + 2u;
  TF_ROUND(13) TF_ROUND(15) TF_ROUND(26) TF_ROUND(6)  x0 += ks0; x1 += ks1 + 3u;
  TF_ROUND(17) TF_ROUND(29) TF_ROUND(16) TF_ROUND(24) x0 += ks1; x1 += ks2 + 4u;
  TF_ROUND(13) TF_ROUND(15) TF_ROUND(26) TF_ROUND(6)  x0 += ks2; x1 += ks0 + 5u;
  const float lo = -0.99999994f;      // nextafter(-1, 0) in f32
  const float sqrt2 = 1.41421356237f; // rounds to 0x3FB504F3
  const unsigned bits = hi ? x1 : x0;
  float f = __uint_as_float((bits >> 9) | 0x3f800000u) - 1.0f;
  float u = fmaxf(lo, f * 2.0f + lo);  // (hi-lo) == 2.0f exactly in f32
  return sqrt2 * erfinv_xla(u);
}

// Fused prologue: blocks 0..127 Smat GEMM, 128..383 Q GEMM, 384..639 YW GEMM,
// 640..767 yn2, 768..895 z0. All independent (need only Wn, Y); per-block
// code identical to the former standalone launches -> bit-exact.
__global__ __launch_bounds__(256) void k_front(
    const float* __restrict__ Wn, const float* __restrict__ Y,
    float* __restrict__ Smat, float* __restrict__ Qm, float* __restrict__ YWm,
    double* __restrict__ dacc, float* __restrict__ vout) {
  __shared__ __align__(16) float smem[4352];  // 17408 B, carved per role
  const int i = blockIdx.x;
  const int t = threadIdx.x;
  if (i < 128) {
    gemm_dev<64, 32, 2>(smem, smem + 32 * 68, Wn, Md, 0, Wn, Md, 1, Smat, Nd,
                        Md, 1.0f, i % 16, i / 16);
  } else if (i < 384) {
    const int j = i - 128;
    gemm_dev<64, 64, 4>(smem, smem + 32 * 68, Wn, Md, 1, Wn, Md, 0, Qm, Md,
                        Nd, 1.0f, j % 16, j / 16);
  } else if (i < 640) {
    const int j = i - 384;
    gemm_dev<64, 64, 4>(smem, smem + 32 * 68, Y, Nd, 0, Wn, Md, 0, YWm, Md,
                        Nd, 1.0f, j % 16, j / 16);
  } else if (i < 768) {
    // yn2 body (was <<<128,256>>>): block index j, stride 128*256
    const int j = i - 640;
    double* red = (double*)smem;
    double s = 0.0;
    for (int idx = j * 256 + t; idx < Bd * Nd; idx += 128 * 256) {
      float y = Y[idx];
      s = fma((double)y, (double)y, s);
    }
    s = wave_reduce_d(s);
    const int lane = t & 63, wid = t >> 6;
    if (lane == 0) red[wid] = s;
    __syncthreads();
    if (t == 0) atomicAdd(&dacc[0], red[0] + red[1] + red[2] + red[3]);
  } else {
    // z0 body (was <<<128,256>>>): X0 recomputed in LDS (bit-exact)
    const int j = i - 768;
    float* x0s = smem;
    x0s[t] = x0_value((unsigned)t, 0);
    x0s[t + 512] = x0_value((unsigned)t, 1);
    x0s[t + 256] = x0_value((unsigned)(t + 256), 0);
    x0s[t + 768] = x0_value((unsigned)(t + 256), 1);
    __syncthreads();
    const int lane = t & 63, wid = t >> 6;
    const int row = j * 4 + wid;  // < 512
    const float4* wr = (const float4*)(Wn + (size_t)row * Md);
    const float4* x4 = (const float4*)x0s;
    float s = 0.f;
#pragma unroll
    for (int e = 0; e < 4; ++e) {
      const float4 w4 = wr[lane + e * 64];
      const float4 xx = x4[lane + e * 64];
      s = fmaf(w4.x, xx.x, s); s = fmaf(w4.y, xx.y, s);
      s = fmaf(w4.z, xx.z, s); s = fmaf(w4.w, xx.w, s);
    }
    s = wave_reduce_f(s);
    if (lane == 0) vout[row] = s;
  }
}

// vout = (vin @ Msym) * scale ; Msym is 512x512 symmetric. One wave per row.
__global__ __launch_bounds__(256) void k_pmv(const float* __restrict__ Mmat,
                                             const float* __restrict__ vin,
                                             float* __restrict__ vout, float scale) {
  const int lane = threadIdx.x & 63, wid = threadIdx.x >> 6;
  const int row = blockIdx.x * 4 + wid;  // < 512
  const float4* mr = (const float4*)(Mmat + (size_t)row * Nd);
  const float4* v4 = (const float4*)vin;
  float s = 0.f;
#pragma unroll
  for (int e = 0; e < 2; ++e) {
    const float4 m4 = mr[lane + e * 64];
    const float4 xx = v4[lane + e * 64];
    s = fmaf(m4.x, xx.x, s); s = fmaf(m4.y, xx.y, s);
    s = fmaf(m4.z, xx.z, s); s = fmaf(m4.w, xx.w, s);
  }
  s = wave_reduce_f(s);
  if (lane == 0) vout[row] = s * scale;
}

__global__ __launch_bounds__(512) void k_pfinal(const float* __restrict__ v99,
                                                const float* __restrict__ v100,
                                                float* __restrict__ cbuf) {
  __shared__ double r99[8], r100[8];
  const int t = threadIdx.x, lane = t & 63, wid = t >> 6;
  double a = (double)v99[t]; a *= a;
  double b = (double)v100[t]; b *= b;
  a = wave_reduce_d(a);
  b = wave_reduce_d(b);
  if (lane == 0) { r99[wid] = a; r100[wid] = b; }
  __syncthreads();
  if (t == 0) {
    double n99 = 0.0, n100 = 0.0;
    for (int i = 0; i < 8; ++i) { n99 += r99[i]; n100 += r100[i]; }
    float c = (float)(8.0 * sqrt(n100 / n99));  // last pre-norm ||X2||
    cbuf[0] = c;
    cbuf[1] = 1.0f / c;  // eta
  }
}

// ALL IHT iterations fused: one workgroup per batch row, loops it=-1..49.
// R12 version VERBATIM (620us): register Gamma, pipelined gather, peeled
// pass-3 barriers fused with norm-dot (10 barriers/iter).
__global__ __launch_bounds__(256, 4) void k_iht_all(
    const float* __restrict__ Q, const float* __restrict__ YW,
    const float* __restrict__ cbuf, float* __restrict__ gdense,
    double* __restrict__ normacc) {
  __shared__ float u[Md];   // holds P (gather result) for the norm dot
  __shared__ float yws[Md];
  __shared__ float sval[Ksp];
  __shared__ int sidx[Ksp];
  __shared__ unsigned histbuf[2][4][256];  // [parity][wave][bin]
  __shared__ unsigned wred[4];
  __shared__ unsigned sel_need, sel_prefix;
  __shared__ double dred0;
  __shared__ int scnt;

  const int t = threadIdx.x;
  const int b = blockIdx.x;
  const int lane = t & 63, wv = t >> 6;
  const float eta = cbuf[1];
  const float4 yw = ((const float4*)(YW + (size_t)b * Md))[t];  // row in regs
  ((float4*)yws)[t] = yw;                                        // + LDS copy
#pragma unroll
  for (int e = 0; e < 8; ++e) ((unsigned*)histbuf)[t + e * 256] = 0u;
  const float* Qt = Q + t * 4;  // per-thread column base; row base is scalar
  float gdr[4] = {0.f, 0.f, 0.f, 0.f};  // dense Gamma, own 4 cols, registers

  // wave-0 merged scan over 4 per-wave histograms; writes sel_prefix/sel_need.
  auto scan_select = [&](unsigned(*hist)[256], unsigned pfx, unsigned nd, int sh) {
    const unsigned c0 = hist[0][lane] + hist[1][lane] + hist[2][lane] + hist[3][lane];
    const unsigned c1 = hist[0][lane + 64] + hist[1][lane + 64] + hist[2][lane + 64] + hist[3][lane + 64];
    const unsigned c2 = hist[0][lane + 128] + hist[1][lane + 128] + hist[2][lane + 128] + hist[3][lane + 128];
    const unsigned c3 = hist[0][lane + 192] + hist[1][lane + 192] + hist[2][lane + 192] + hist[3][lane + 192];
    unsigned s0 = c0, s1 = c1, s2 = c2, s3 = c3;  // suffix scans (4 chunks)
#pragma unroll
    for (int off = 1; off < 64; off <<= 1) {
      const unsigned y0 = __shfl_down(s0, off), y1 = __shfl_down(s1, off);
      const unsigned y2 = __shfl_down(s2, off), y3 = __shfl_down(s3, off);
      if (lane + off < 64) { s0 += y0; s1 += y1; s2 += y2; s3 += y3; }
    }
    const unsigned T1 = __builtin_amdgcn_readfirstlane(s1);
    const unsigned T2 = __builtin_amdgcn_readfirstlane(s2);
    const unsigned T3 = __builtin_amdgcn_readfirstlane(s3);
    const unsigned i0 = s0 + T1 + T2 + T3;  // incl count, bin = lane
    const unsigned i1 = s1 + T2 + T3;       // bin = lane+64
    const unsigned i2 = s2 + T3;            // bin = lane+128
    const unsigned i3 = s3;                 // bin = lane+192
    if (i0 >= nd && i0 - c0 < nd) { sel_prefix = pfx | ((unsigned)lane << sh); sel_need = nd - (i0 - c0); }
    if (i1 >= nd && i1 - c1 < nd) { sel_prefix = pfx | ((unsigned)(lane + 64) << sh); sel_need = nd - (i1 - c1); }
    if (i2 >= nd && i2 - c2 < nd) { sel_prefix = pfx | ((unsigned)(lane + 128) << sh); sel_need = nd - (i2 - c2); }
    if (i3 >= nd && i3 - c3 < nd) { sel_prefix = pfx | ((unsigned)(lane + 192) << sh); sel_need = nd - (i3 - c3); }
  };

  for (int it = -1; it < IHT; ++it) {
    float vals[4];
    unsigned key[4];
    int cnt = 0;
    if (it >= 0) {
      cnt = scnt;
      float4 p = make_float4(0.f, 0.f, 0.f, 0.f);
      // double-buffered 8-row pipeline: issue next batch's loads before the
      // current batch's fmafs. Per-component k-ascending order -> bit-exact.
      float4 qa[8], qb[8];
      float ga[8], gb[8];
      auto LOAD8 = [&](float4* q, float* g, int kk) {
#pragma unroll
        for (int j = 0; j < 8; ++j) {
          const int id = __builtin_amdgcn_readfirstlane(sidx[kk + j]);
          g[j] = rfl_f(sval[kk + j]);
          q[j] = *(const float4*)(Qt + (size_t)id * Md);
        }
      };
      auto FMA8 = [&](const float4* q, const float* g) {
#pragma unroll
        for (int j = 0; j < 8; ++j) p.x = fmaf(g[j], q[j].x, p.x);
#pragma unroll
        for (int j = 0; j < 8; ++j) p.y = fmaf(g[j], q[j].y, p.y);
#pragma unroll
        for (int j = 0; j < 8; ++j) p.z = fmaf(g[j], q[j].z, p.z);
#pragma unroll
        for (int j = 0; j < 8; ++j) p.w = fmaf(g[j], q[j].w, p.w);
      };
      int k = 0;
      const int nfull = cnt & ~7;
      if (nfull >= 8) {
        LOAD8(qa, ga, 0);
        k = 8;
        for (; k + 16 <= nfull; k += 16) {
          LOAD8(qb, gb, k);
          FMA8(qa, ga);
          LOAD8(qa, ga, k + 8);
          FMA8(qb, gb);
        }
        if (k + 8 <= nfull) {  // one full batch beyond qa remains
          LOAD8(qb, gb, k);
          FMA8(qa, ga);
          FMA8(qb, gb);
          k += 8;
        } else {
          FMA8(qa, ga);
        }
      }
      for (; k < cnt; ++k) {
        const int id = __builtin_amdgcn_readfirstlane(sidx[k]);
        const float g = rfl_f(sval[k]);
        const float4 q = *(const float4*)(Qt + (size_t)id * Md);
        p.x = fmaf(g, q.x, p.x); p.y = fmaf(g, q.y, p.y);
        p.z = fmaf(g, q.z, p.z); p.w = fmaf(g, q.w, p.w);
      }
      ((float4*)u)[t] = p;  // u holds P for the norm dot (read by wave 1)
      // U = uu + Gamma_dense, entirely in registers
      vals[0] = -(eta * (p.x - yw.x)) + gdr[0];
      vals[1] = -(eta * (p.y - yw.y)) + gdr[1];
      vals[2] = -(eta * (p.z - yw.z)) + gdr[2];
      vals[3] = -(eta * (p.w - yw.w)) + gdr[3];
      // no barrier here: histbuf[1] was zeroed last iteration (pass-0 phase,
      // >=2 barriers ago); F1 below covers P visibility + pass-3 atomics.
    } else {
      vals[0] = eta * yw.x; vals[1] = eta * yw.y;
      vals[2] = eta * yw.z; vals[3] = eta * yw.w;
      __syncthreads();      // B0: init zeros of histbuf + yws visible
    }
#pragma unroll
    for (int e = 0; e < 4; ++e) key[e] = __float_as_uint(vals[e]) & 0x7fffffffu;

    // ---- peeled radix pass 3 (pb=1): atomics by all waves ----
#pragma unroll
    for (int e = 0; e < 4; ++e) atomicAdd(&histbuf[1][wv][key[e] >> 24], 1u);
    __syncthreads();  // F1: P (u[]) + pass-3 atomics visible
    // ---- specialized phase: scan | norm-dot | re-zero histbuf[0] ----
    if (wv == 0) {
      scan_select(histbuf[1], 0u, Ksp + 1, 24);
    } else if (wv == 1) {
      if (it >= 1) {
        // norm-dot: cnt <= 64, one wave. Same per-lane mapping and shuffle
        // reduce tree as R8's wave-0 computation -> bit-identical sum.
        double part = 0.0;
        if (lane < cnt) {
          const int id = sidx[lane];
          part = (double)sval[lane] * ((double)u[id] - 2.0 * (double)yws[id]);
        }
        part = wave_reduce_d(part);
        if (lane == 0) dred0 = part;
      }
    } else {
      // waves 2,3: zero histbuf[0] (1024 words; last read: previous
      // iteration's pass-0 scan, >=3 barriers ago). 512 words per wave.
      unsigned* hz = (unsigned*)histbuf[0] + (wv - 2) * 512;
#pragma unroll
      for (int e = 0; e < 8; ++e) hz[lane + e * 64] = 0u;
    }
    __syncthreads();  // F2: sel_*, dred0, zeros visible
    unsigned prefix = sel_prefix;
    unsigned need = sel_need;
    unsigned pmask = 0xFF000000u;

    // ---- radix passes 2..0 (parallel, 2 barriers each) ----
#pragma unroll
    for (int pass = 2; pass >= 0; --pass) {
      const int sh = 8 * pass;
      const int pb = pass & 1;  // 0,1,0
      unsigned(*hist)[256] = histbuf[pb];
#pragma unroll
      for (int e = 0; e < 4; ++e)
        if ((key[e] & pmask) == prefix) atomicAdd(&hist[wv][(key[e] >> sh) & 255u], 1u);
      if (pass == 2 && it >= 1 && t == 0) atomicAdd(&normacc[it - 1], dred0);
      __syncthreads();  // A: atomics visible
      // zero the opposite buffer (next pass / next iteration's pass 3)
      unsigned* hz = histbuf[pb ^ 1][wv];
      hz[lane] = 0u; hz[lane + 64] = 0u; hz[lane + 128] = 0u; hz[lane + 192] = 0u;
      if (wv == 0) scan_select(hist, prefix, need, sh);
      __syncthreads();  // B: sel_* and zeros visible
      prefix = sel_prefix;
      need = sel_need;
      pmask |= (255u << sh);
    }
    const unsigned Tbits = prefix;

    // ---- ordered compaction (deterministic, ascending column order) ----
    unsigned keep = 0u;
    unsigned myc = 0u;
#pragma unroll
    for (int e = 0; e < 4; ++e)
      if (key[e] > Tbits) { keep |= (1u << e); ++myc; }
    // update dense-Gamma registers for next iteration
    gdr[0] = (keep & 1u) ? vals[0] : 0.f;
    gdr[1] = (keep & 2u) ? vals[1] : 0.f;
    gdr[2] = (keep & 4u) ? vals[2] : 0.f;
    gdr[3] = (keep & 8u) ? vals[3] : 0.f;
    unsigned x = myc;
#pragma unroll
    for (int off = 1; off < 64; off <<= 1) {  // wave inclusive prefix scan
      const unsigned y = __shfl_up(x, off);
      if (lane >= off) x += y;
    }
    if (lane == 63) wred[wv] = x;  // wave total
    __syncthreads();  // C1: wred visible (old sidx/sval reads done pre-F2)
    unsigned addlo = 0u;
    for (int w2 = 0; w2 < wv; ++w2) addlo += wred[w2];
    int base = (int)(x + addlo) - (int)myc;  // exclusive prefix in thread order
#pragma unroll
    for (int e = 0; e < 4; ++e) {
      if (keep & (1u << e)) {
        sidx[base] = t * 4 + e;
        sval[base] = vals[e];
        ++base;
      }
    }
    if (t == 0) scnt = (int)(wred[0] + wred[1] + wred[2] + wred[3]);
    if (it == IHT - 1) {
      float4 g;
      g.x = gdr[0]; g.y = gdr[1]; g.z = gdr[2]; g.w = gdr[3];
      ((float4*)(gdense + (size_t)b * Md))[t] = g;
    }
    __syncthreads();  // C2: publish sidx/sval/scnt for next iteration
  }

  // ---- epilogue: norms[49] term for final Gamma (same math as R3 k_norm50) --
  const int cnt = scnt;
  if (wv == 0) {
    double part = 0.0;
    if (lane < cnt) {
      const int id = sidx[lane];
      float acc2 = 0.f;
      for (int k = 0; k < cnt; ++k)
        acc2 = fmaf(sval[k], Q[(size_t)sidx[k] * Md + id], acc2);
      part = (double)sval[lane] * ((double)acc2 - 2.0 * (double)yws[id]);
    }
    part = wave_reduce_d(part);
    if (lane == 0) atomicAdd(&normacc[IHT - 1], part);
  }
}

// Fused epilogue: blocks 0..255 X = Wn @ Gamma GEMM; block 256 computes norms.
__global__ __launch_bounds__(256) void k_back(
    const float* __restrict__ Wn, const float* __restrict__ G,
    float* __restrict__ X, const double* __restrict__ dacc,
    float* __restrict__ onorms) {
  __shared__ __align__(16) float smem[4352];
  const int i = blockIdx.x;
  if (i < 256) {
    gemm_dev<64, 32, 2>(smem, smem + 32 * 68, Wn, Md, 0, G, Md, 0, X, Md, Md,
                        1.0f, i % 32, i / 32);
  } else {
    const int t = threadIdx.x;
    if (t < IHT) {
      const double yn2 = dacc[0];
      double r2 = yn2 + dacc[1 + t];
      if (r2 < 0.0) r2 = 0.0;
      onorms[t] = (float)(sqrt(r2) / sqrt(yn2));
    }
  }
}

extern "C" void kernel_launch(void* const* d_in, const int* in_sizes, int n_in,
                              void* d_out, int out_size, void* d_ws, size_t ws_size,
                              hipStream_t stream) {
  (void)in_sizes; (void)n_in; (void)out_size; (void)ws_size;  // K hardcoded = 64
  const float* Y = (const float*)d_in[0];  // [1024,512]
  const float* W = (const float*)d_in[1];  // [512,1024]
  float* out = (float*)d_out;
  float* outX = out;                   // [512,1024]
  float* outG = out + Nd * Md;         // [1024,1024]
  float* outN = outG + Bd * Md;        // [50]

  // workspace layout (~11.5 MB)
  char* wsb = (char*)d_ws;
  double* dacc = (double*)wsb;               // 51 doubles
  float* cbuf = (float*)(wsb + 512);         // [0]=c, [1]=eta
  float* Wn = (float*)(wsb + 1024);          // 512*1024
  float* Q = Wn + Nd * Md;                   // 1024*1024
  float* YW = Q + Md * Md;                   // 1024*1024
  float* Smat = YW + Bd * Md;                // 512*512
  float* S2 = Smat + Nd * Nd;                // 512*512
  float* cnorm = S2 + Nd * Nd;               // 1024
  float* X0 = cnorm + Md;                    // 1024 (unused, kept for layout)
  float* V = X0 + Md;                        // 4*512 power-iter slots

  k_colnorm<<<4, 256, 0, stream>>>(W, cnorm, dacc);  // also zeroes dacc
  k_normalize<<<2048, 256, 0, stream>>>(W, cnorm, Wn);

  // fused independent prologue: Smat = Wn Wn^T, Q = Wn^T Wn, YW = Y Wn,
  // Yn2 accumulation, z0 = X0 @ Wn^T — one 896-block launch.
  k_front<<<896, 256, 0, stream>>>(Wn, Y, Smat, Q, YW, dacc, V);

  // S2 = Smat*Smat/64 (depends on Smat)
  k_gemm_t<64, 32, 2><<<dim3(16, 8), 256, 0, stream>>>(Smat, Nd, 0, Smat, Nd, 0, S2, Nd, Nd, 0.015625f);

  // power method in Z-space: 49 steps of S2, 2 steps of S/8 (untouched math —
  // eta must stay bit-identical)
  float* pin = V;
  float* pout = V + 512;
  for (int i = 0; i < 49; ++i) {
    k_pmv<<<128, 256, 0, stream>>>(S2, pin, pout, 1.0f);
    float* tp = pin; pin = pout; pout = tp;
  }
  k_pmv<<<128, 256, 0, stream>>>(Smat, pin, V + 1024, 0.125f);        // v99
  k_pmv<<<128, 256, 0, stream>>>(Smat, V + 1024, V + 1536, 0.125f);   // v100
  k_pfinal<<<1, 512, 0, stream>>>(V + 1024, V + 1536, cbuf);

  // IHT: init + 50 iterations + final norm term, all in ONE launch
  k_iht_all<<<1024, 256, 0, stream>>>(Q, YW, cbuf, outG, dacc + 1);

  // fused epilogue: X = Wn @ Gamma + norms finalize
  k_back<<<257, 256, 0, stream>>>(Wn, outG, outX, dacc, outN);
}